// Round 6
// baseline (591.077 us; speedup 1.0000x reference)
//
#include <hip/hip_runtime.h>

// TopKActivation: per row of [4096, 16384] fp32, keep top-k (k=128), zero rest.
// R7/R8/R9 post-mortem: three hot-loop structures all hit 190-206us with both
// pipes idle -- the common floor is the barrier structure: __syncthreads emits
// s_waitcnt vmcnt(0) before s_barrier, forcing every wave to drain its NT
// stores to HBM (~1us) before the tiny select phase. R10 removes the drain:
//   * Window-containing groups (~10.7%) are NOT stored in phase 1; their raw
//     uint4 is captured in 4 register slots (overflow: rare L2 re-load).
//     Phase-1 stores and fix-up stores are address-DISJOINT -> no ordering
//     needed between phases.
//   * Fast-path barriers are `s_waitcnt lgkmcnt(0); s_barrier` (asm) -- LDS
//     visibility only; NT stores drain lazily, kernel-end drain completes them.
//   * Hot loop: pure load/transform/store + register capture. Candidate push
//     (LDS atomics) runs post-loop from registers. No re-reads.
// Select (wave0 hist + 17-iter bisect) verbatim from R9. Exact fallback uses
// regular __syncthreads (vmcnt-draining -> its full rewrite is ordered).

constexpr int COLS = 16384;
constexpr int NT   = 256;             // threads per block (4 waves)
constexpr int NG   = COLS / 4;        // 4096 float4-groups per row
constexpr int GPT  = NG / NT;         // 16 groups per thread
constexpr int NW   = NT / 64;         // 4 waves
constexpr int CAP  = 2048;            // LDS candidate buffer
constexpr int NBIN = 64;              // histogram bins over [A, B)

typedef float v4f __attribute__((ext_vector_type(4)));

// LDS-only barrier: do NOT drain vmcnt (that's the point).
#define BAR_LGKM() asm volatile("s_waitcnt lgkmcnt(0)\n\ts_barrier" ::: "memory")

// Monotone float->uint key: order(key) == order(float), all finite values.
__device__ __forceinline__ unsigned int f2key(float f) {
  unsigned int b = __float_as_uint(f);
  return b ^ ((unsigned int)((int)b >> 31) | 0x80000000u);
}
__device__ __forceinline__ float key2f(unsigned int k) {
  unsigned int b = (k & 0x80000000u) ? (k ^ 0x80000000u) : ~k;
  return __uint_as_float(b);
}

__global__ void __launch_bounds__(NT, 6)
topk_scatter_kernel(const float* __restrict__ x, const int* __restrict__ kptr,
                    float* __restrict__ out) {
  const int t    = threadIdx.x;
  const int lane = t & 63;
  const int wid  = t >> 6;
  const long long row = blockIdx.x;
  const int K = *kptr;   // 128

  __shared__ int redA[NW], redB[NW];        // bracket counts per wave
  __shared__ int red2[2][NW];               // fallback reduce, parity-buffered
  __shared__ unsigned int   cand[CAP];      // window candidate keys
  __shared__ unsigned short candcol[CAP];   // window candidate columns
  __shared__ int hist[NBIN];                // window histogram (wave0-built)
  __shared__ int cand_n;
  __shared__ int c2n;                       // wave0 bin-compaction counter
  __shared__ unsigned int sT;               // broadcast: threshold key
  __shared__ int sE, sR;                    // broadcast: eq-count, keep-count
  __shared__ unsigned int flags[COLS / 32]; // fallback tie bitmask (2 KB);
                                            // reused as wave0's cand2[128]

  const uint4* xrow = reinterpret_cast<const uint4*>(x + row * COLS);
  v4f*         orow = reinterpret_cast<v4f*>(out + row * COLS);

  // Window [A, B): key range B-A = 0x59999A < 2^23, so bin = (k-A)>>17 < 64.
  const unsigned int A = f2key(1.9f);
  const unsigned int B = f2key(3.2f);

  if (t < NBIN) hist[t] = 0;
  if (t == 0) cand_n = 0;
  __syncthreads();                                   // barrier 0 (cold, cheap)

  // ---- hot loop: pipelined; no LDS, no atomics, no ballots ---------------
  int cwA = 0, cwB = 0;
  uint4 d0, d1, d2, d3;                    // deferred (window) group capture
  int dn = 0;                              // deferred count (may exceed 4)
  unsigned int dpos = 0;                   // 4-bit group idx per slot
  unsigned int dmask = 0;                  // all deferred groups (16 bits)

  {
    uint4 bA[2], bB[2];
    #define LOADC(c, b) { b[0] = xrow[(2*(c)+0)*NT + t]; \
                          b[1] = xrow[(2*(c)+1)*NT + t]; }
    #define PROCC(c, b)                                                       \
      _Pragma("unroll")                                                       \
      for (int i = 0; i < 2; ++i) {                                           \
        const int r = 2*(c) + i;                                              \
        const uint4 u = b[i];                                                 \
        const unsigned int k0 = f2key(__uint_as_float(u.x));                  \
        const unsigned int k1 = f2key(__uint_as_float(u.y));                  \
        const unsigned int k2 = f2key(__uint_as_float(u.z));                  \
        const unsigned int k3 = f2key(__uint_as_float(u.w));                  \
        cwA += (k0 >= A) + (k1 >= A) + (k2 >= A) + (k3 >= A);                 \
        cwB += (k0 >= B) + (k1 >= B) + (k2 >= B) + (k3 >= B);                 \
        const bool anyw = ((k0 >= A) & (k0 < B)) | ((k1 >= A) & (k1 < B)) |   \
                          ((k2 >= A) & (k2 < B)) | ((k3 >= A) & (k3 < B));    \
        if (anyw) {                                                           \
          dmask |= (1u << r);                                                 \
          if (dn < 4) {                                                       \
            dpos |= (unsigned int)r << (4 * dn);                              \
            if      (dn == 0) d0 = u;                                         \
            else if (dn == 1) d1 = u;                                         \
            else if (dn == 2) d2 = u;                                         \
            else              d3 = u;                                         \
          }                                                                   \
          ++dn;                                                               \
        } else {                                                              \
          v4f vals;                                                           \
          vals[0] = (k0 >= B) ? __uint_as_float(u.x) : 0.0f;                  \
          vals[1] = (k1 >= B) ? __uint_as_float(u.y) : 0.0f;                  \
          vals[2] = (k2 >= B) ? __uint_as_float(u.z) : 0.0f;                  \
          vals[3] = (k3 >= B) ? __uint_as_float(u.w) : 0.0f;                  \
          __builtin_nontemporal_store(vals, &orow[r * NT + t]);               \
        }                                                                     \
      }
    LOADC(0, bA); LOADC(1, bB);
    PROCC(0, bA); LOADC(2, bA);
    PROCC(1, bB); LOADC(3, bB);
    PROCC(2, bA); LOADC(4, bA);
    PROCC(3, bB); LOADC(5, bB);
    PROCC(4, bA); LOADC(6, bA);
    PROCC(5, bB); LOADC(7, bB);
    PROCC(6, bA);
    PROCC(7, bB);
    #undef LOADC
    #undef PROCC
  }

  // ---- candidate push from registers (off the stream path) ---------------
  {
    #define PUSHG(r, u)                                                       \
      _Pragma("unroll")                                                       \
      for (int j = 0; j < 4; ++j) {                                           \
        const unsigned int k = f2key(__uint_as_float((&(u).x)[j]));           \
        if (k >= A && k < B) {                                                \
          const int p = atomicAdd(&cand_n, 1);                                \
          if (p < CAP) {                                                      \
            cand[p] = k;                                                      \
            candcol[p] = (unsigned short)(4 * ((r) * NT + t) + j);            \
          }                                                                   \
        }                                                                     \
      }
    if (dn > 0) { const int r = dpos & 15;         PUSHG(r, d0); }
    if (dn > 1) { const int r = (dpos >> 4) & 15;  PUSHG(r, d1); }
    if (dn > 2) { const int r = (dpos >> 8) & 15;  PUSHG(r, d2); }
    if (dn > 3) { const int r = (dpos >> 12) & 15; PUSHG(r, d3); }
    if (dn > 4) {                                  // rare: re-load extras
      unsigned int m = dmask;
      m &= m - 1; m &= m - 1; m &= m - 1; m &= m - 1;
      while (m) {
        const int r = __builtin_ctz(m); m &= m - 1;
        const uint4 u = xrow[r * NT + t];
        PUSHG(r, u);
      }
    }
    #undef PUSHG
  }

  #pragma unroll
  for (int off = 32; off; off >>= 1) {
    cwA += __shfl_down(cwA, off);
    cwB += __shfl_down(cwB, off);
  }
  if (lane == 0) { redA[wid] = cwA; redB[wid] = cwB; }
  BAR_LGKM();                                        // barrier 1: LDS only

  int cA = 0, cBv = 0;
  #pragma unroll
  for (int w = 0; w < NW; ++w) { cA += redA[w]; cBv += redB[w]; }

  const bool fast = (cA >= K) && (cBv < K) && ((cA - cBv) <= CAP);

  if (fast) {
    const int NC = cA - cBv;                         // exact window count
    // ---- wave 0: build hist from cand list, then select (no barriers) ---
    if (wid == 0) {
      for (int j0 = 0; j0 < NC; j0 += 64) {
        const int j = j0 + lane;
        if (j < NC) atomicAdd(&hist[(cand[j] - A) >> 17], 1);
      }
      asm volatile("s_waitcnt lgkmcnt(0)" ::: "memory");
      // suffix sums: suf[b] = count of window cands with bin >= b
      int suf = hist[lane];                          // NBIN == 64 lanes
      #pragma unroll
      for (int off = 1; off < 64; off <<= 1) {
        const int v = __shfl_down(suf, off);
        if (lane + off < 64) suf += v;
      }
      const unsigned long long m = __ballot(cBv + suf >= K);
      const int bstar = 63 - __clzll((long long)m);  // threshold bin
      const int s_b  = __shfl(suf, bstar);
      const int s_b1 = (bstar < 63) ? __shfl(suf, bstar + 1) : 0;
      const int nb = s_b - s_b1;                     // cands in bin (>=1)
      const unsigned int binlo = A + ((unsigned int)bstar << 17);
      const unsigned int binhi = binlo + (1u << 17) - 1u;
      unsigned int lo, hi;
      int cnt_lo, cnt_hi1;
      if (nb <= 128) {
        // compact bin-b* cands into cand2 (reuse flags); intra-wave ordered
        unsigned int* cand2 = (unsigned int*)flags;
        cand2[lane] = 0u; cand2[64 + lane] = 0u;     // 0 < binlo: never counts
        if (lane == 0) c2n = 0;
        for (int j0 = 0; j0 < NC; j0 += 64) {
          const int j = j0 + lane;
          const unsigned int v = (j < NC) ? cand[j] : 0u;
          if (v >= binlo && v <= binhi) {
            const int p = atomicAdd(&c2n, 1);
            cand2[p] = v;
          }
        }
        const unsigned int r0 = cand2[lane];
        const unsigned int r1 = cand2[64 + lane];
        lo = binlo; hi = binhi;
        cnt_lo = cBv + s_b; cnt_hi1 = cBv + s_b1;
        const int base2 = cBv + s_b1;
        while (lo < hi) {                            // exactly 17 iterations
          const unsigned int mid = lo + ((hi - lo) >> 1) + 1u;
          const int c = base2 + __popcll(__ballot(r0 >= mid))
                              + __popcll(__ballot(r1 >= mid));
          if (c >= K) { lo = mid; cnt_lo = c; }
          else        { hi = mid - 1u; cnt_hi1 = c; }
        }
      } else {
        // adversarial bin (>128 cands): scan full cand list per iteration
        lo = A; hi = B - 1u; cnt_lo = cA; cnt_hi1 = cBv;
        while (lo < hi) {
          const unsigned int mid = lo + ((hi - lo) >> 1) + 1u;
          int c = cBv;
          for (int j0 = 0; j0 < NC; j0 += 64) {
            const unsigned int v = (j0 + lane < NC) ? cand[j0 + lane] : 0u;
            c += __popcll(__ballot(v >= mid));
          }
          if (c >= K) { lo = mid; cnt_lo = c; }
          else        { hi = mid - 1u; cnt_hi1 = c; }
        }
      }
      if (lane == 0) { sT = lo; sE = cnt_lo - cnt_hi1; sR = K - cnt_hi1; }
    }
    BAR_LGKM();                                      // barrier 2: LDS only

    // ---- fix-up: store ONLY deferred groups (disjoint from phase 1) ------
    const unsigned int T = sT;
    const int Ev = sE, Rv = sR;
    const bool needR = (Ev != Rv);     // duplicates straddling the boundary
    #define FIXG(r, u)                                                        \
      {                                                                       \
        v4f vals;                                                             \
        _Pragma("unroll")                                                     \
        for (int j = 0; j < 4; ++j) {                                         \
          const unsigned int k = f2key(__uint_as_float((&(u).x)[j]));         \
          bool keep;                                                          \
          if (k > T) {                                                        \
            keep = true;                                                      \
          } else if (k == T) {                                                \
            if (!needR) {                                                     \
              keep = true;                                                    \
            } else {                                                          \
              const int col = 4 * ((r) * NT + t) + j;                         \
              int rk = 0;                                                     \
              for (int q = 0; q < NC; ++q)                                    \
                rk += (cand[q] == T && candcol[q] < col) ? 1 : 0;             \
              keep = (rk < Rv);                                               \
            }                                                                 \
          } else {                                                            \
            keep = false;                                                     \
          }                                                                   \
          vals[j] = keep ? __uint_as_float((&(u).x)[j]) : 0.0f;               \
        }                                                                     \
        __builtin_nontemporal_store(vals, &orow[(r) * NT + t]);               \
      }
    if (dn > 0) { const int r = dpos & 15;         FIXG(r, d0); }
    if (dn > 1) { const int r = (dpos >> 4) & 15;  FIXG(r, d1); }
    if (dn > 2) { const int r = (dpos >> 8) & 15;  FIXG(r, d2); }
    if (dn > 3) { const int r = (dpos >> 12) & 15; FIXG(r, d3); }
    if (dn > 4) {                                  // rare: re-load extras
      unsigned int m = dmask;
      m &= m - 1; m &= m - 1; m &= m - 1; m &= m - 1;
      while (m) {
        const int r = __builtin_ctz(m); m &= m - 1;
        const uint4 u = xrow[r * NT + t];
        FIXG(r, u);
      }
    }
    #undef FIXG
    return;
  }

  // ---- exact fallback: bitwise bisection with global re-reads ------------
  // Uses regular __syncthreads (vmcnt-draining) -> phase-1 NT stores are
  // complete before the full rewrite below. Correctness path only.
  unsigned int T;
  int Ev, Rv;
  {
    unsigned int lo = 0u, hi = 0xFFFFFFFFu;
    int cnt_lo = COLS, cnt_hi1 = 0;
    int base = 0, cN = 0;
    bool compacted = false;
    int par = 0;
    while (lo < hi) {
      const unsigned int mid = lo + ((hi - lo) >> 1) + 1u;
      int c;
      if (!compacted) {
        int cw = 0;
        for (int r = 0; r < GPT; ++r) {
          const uint4 u = xrow[r * NT + t];
          cw += (f2key(__uint_as_float(u.x)) >= mid);
          cw += (f2key(__uint_as_float(u.y)) >= mid);
          cw += (f2key(__uint_as_float(u.z)) >= mid);
          cw += (f2key(__uint_as_float(u.w)) >= mid);
        }
        #pragma unroll
        for (int off = 32; off; off >>= 1) cw += __shfl_down(cw, off);
        if (lane == 0) red2[par][wid] = cw;
        __syncthreads();
        c = 0;
        #pragma unroll
        for (int w = 0; w < NW; ++w) c += red2[par][w];
        par ^= 1;
      } else {
        int cw = 0;
        for (int j0 = 0; j0 < cN; j0 += 64) {
          const int j = j0 + lane;
          const unsigned int v = (j < cN) ? cand[j] : 0u;
          cw += __popcll(__ballot(v >= mid));
        }
        c = base + cw;
      }
      if (c >= K) { lo = mid; cnt_lo = c; }
      else        { hi = mid - 1u; cnt_hi1 = c; }

      if (!compacted && lo < hi && (cnt_lo - cnt_hi1) <= CAP) {
        if (t == 0) cand_n = 0;
        __syncthreads();
        for (int r = 0; r < GPT; ++r) {
          const uint4 u = xrow[r * NT + t];
          const unsigned int kk[4] = {
            f2key(__uint_as_float(u.x)), f2key(__uint_as_float(u.y)),
            f2key(__uint_as_float(u.z)), f2key(__uint_as_float(u.w)) };
          #pragma unroll
          for (int j = 0; j < 4; ++j) {
            if (kk[j] >= lo && kk[j] <= hi) {
              const int p = atomicAdd(&cand_n, 1);
              if (p < CAP) cand[p] = kk[j];
            }
          }
        }
        __syncthreads();
        cN = cnt_lo - cnt_hi1;
        base = cnt_hi1;
        compacted = true;
      }
    }
    T = lo; Ev = cnt_lo - cnt_hi1; Rv = K - cnt_hi1;
  }

  const bool needR = (Ev != Rv);
  if (needR) {
    for (int w = t; w < COLS / 32; w += NT) flags[w] = 0u;
    __syncthreads();
    for (int r = 0; r < GPT; ++r) {
      const int g = r * NT + t;
      const uint4 u = xrow[g];
      const unsigned int kk[4] = {
        f2key(__uint_as_float(u.x)), f2key(__uint_as_float(u.y)),
        f2key(__uint_as_float(u.z)), f2key(__uint_as_float(u.w)) };
      #pragma unroll
      for (int j = 0; j < 4; ++j) {
        if (kk[j] == T) {
          const int col = 4 * g + j;
          atomicOr(&flags[col >> 5], 1u << (col & 31));
        }
      }
    }
    __syncthreads();
  }

  // full write pass (fallback only; overwrites phase-1 stores, same thread)
  for (int r = 0; r < GPT; ++r) {
    const int g = r * NT + t;
    const uint4 u = xrow[g];
    const unsigned int kk[4] = {
      f2key(__uint_as_float(u.x)), f2key(__uint_as_float(u.y)),
      f2key(__uint_as_float(u.z)), f2key(__uint_as_float(u.w)) };
    v4f vals;
    #pragma unroll
    for (int j = 0; j < 4; ++j) {
      bool keep;
      if (kk[j] > T) {
        keep = true;
      } else if (kk[j] == T) {
        if (!needR) {
          keep = true;
        } else {
          const int col = 4 * g + j;
          const int w_hi = col >> 5;
          int rank = 0;
          for (int w = 0; w < w_hi; ++w) rank += __popc(flags[w]);
          rank += __popc(flags[w_hi] & ((1u << (col & 31)) - 1u));
          keep = (rank < Rv);
        }
      } else {
        keep = false;
      }
      vals[j] = keep ? key2f(kk[j]) : 0.0f;
    }
    __builtin_nontemporal_store(vals, &orow[g]);
  }
}

extern "C" void kernel_launch(void* const* d_in, const int* in_sizes, int n_in,
                              void* d_out, int out_size, void* d_ws, size_t ws_size,
                              hipStream_t stream) {
  const float* x    = (const float*)d_in[0];
  const int*   kptr = (const int*)d_in[1];
  float*       out  = (float*)d_out;
  const int rows = in_sizes[0] / COLS;  // 4096
  topk_scatter_kernel<<<rows, NT, 0, stream>>>(x, kptr, out);
}

// Round 7
// 465.870 us; speedup vs baseline: 1.2688x; 1.2688x over previous
//
#include <hip/hip_runtime.h>

// TopKActivation: per row of [4096, 16384] fp32, keep top-k (k=128), zero rest.
// R10 post-mortem: skipping window groups in phase 1 made the NT store stream
// hole-y at 16B granularity -> HBM read-modify-write, WRITE 318->553MB, 300us.
// Root cause shared by R7-R10: __builtin_nontemporal_store completes at HBM
// (~900ns) not L2 (~200ns), so (a) every __syncthreads vmcnt(0) drain waits
// ~1us on store acks, and (b) in-order vmem issue means a backed-up HBM write
// queue blocks the wave's NEXT LOADS -> load MLP capped -> 2.2-3.0 TB/s wall.
// R11 = R9 structure (best verified traffic: FETCH 139/WRITE 318) with ONE
// change: regular cached stores everywhere. Stores ack at L2 (waves run
// ahead; L2 writes back asynchronously), barrier drains become cheap, and
// scalar fix-ups merge into L2-resident lines (no partial-line RMW).
// Select (wave0 hist + 17-iter bisect) + exact fallback verbatim from R9.

constexpr int COLS = 16384;
constexpr int NT   = 256;             // threads per block (4 waves)
constexpr int NG   = COLS / 4;        // 4096 float4-groups per row
constexpr int GPT  = NG / NT;         // 16 groups per thread
constexpr int NW   = NT / 64;         // 4 waves
constexpr int CAP  = 2048;            // LDS candidate buffer
constexpr int NBIN = 64;              // histogram bins over [A, B)

typedef float v4f __attribute__((ext_vector_type(4)));

// Monotone float->uint key: order(key) == order(float), all finite values.
__device__ __forceinline__ unsigned int f2key(float f) {
  unsigned int b = __float_as_uint(f);
  return b ^ ((unsigned int)((int)b >> 31) | 0x80000000u);
}
__device__ __forceinline__ float key2f(unsigned int k) {
  unsigned int b = (k & 0x80000000u) ? (k ^ 0x80000000u) : ~k;
  return __uint_as_float(b);
}

__device__ __forceinline__ void load_chunk(const uint4* __restrict__ xrow,
                                           int t, int c, uint4 b[4]) {
  #pragma unroll
  for (int i = 0; i < 4; ++i) b[i] = xrow[(4 * c + i) * NT + t];
}

__device__ __forceinline__ void proc_chunk(v4f* __restrict__ orow,
                                           unsigned int* __restrict__ cand,
                                           unsigned short* __restrict__ candcol,
                                           int* __restrict__ cand_n,
                                           int t, int lane, int c,
                                           const uint4 b[4],
                                           unsigned int A, unsigned int B,
                                           int& cwA, int& cwB) {
  unsigned int kk[16];
  // transform + counts + decided stores (branchless, dense full lines)
  #pragma unroll
  for (int i = 0; i < 4; ++i) {
    const int r = 4 * c + i;
    const uint4 u = b[i];
    kk[4 * i + 0] = f2key(__uint_as_float(u.x));
    kk[4 * i + 1] = f2key(__uint_as_float(u.y));
    kk[4 * i + 2] = f2key(__uint_as_float(u.z));
    kk[4 * i + 3] = f2key(__uint_as_float(u.w));
    #pragma unroll
    for (int j = 0; j < 4; ++j) {
      cwA += (kk[4 * i + j] >= A);
      cwB += (kk[4 * i + j] >= B);
    }
    v4f vals;
    vals[0] = (kk[4 * i + 0] >= B) ? __uint_as_float(u.x) : 0.0f;
    vals[1] = (kk[4 * i + 1] >= B) ? __uint_as_float(u.y) : 0.0f;
    vals[2] = (kk[4 * i + 2] >= B) ? __uint_as_float(u.z) : 0.0f;
    vals[3] = (kk[4 * i + 3] >= B) ? __uint_as_float(u.w) : 0.0f;
    orow[r * NT + t] = vals;                 // cached store: acks at L2
  }
  // aggregated candidate push from registers (wave-uniform guards)
  #pragma unroll
  for (int p = 0; p < 16; ++p) {
    const unsigned int k = kk[p];
    const bool isw = (k >= A) & (k < B);
    const unsigned long long m = __ballot(isw);
    if (m) {
      const int leader = (int)__ffsll((long long)m) - 1;
      int base = 0;
      if (lane == leader) base = atomicAdd(cand_n, __popcll(m));
      base = __shfl(base, leader);
      if (isw) {
        const int rank = (int)__popcll(m & ((1ull << lane) - 1ull));
        const int idx = base + rank;
        if (idx < CAP) {
          const int r = 4 * c + (p >> 2);
          cand[idx]    = k;
          candcol[idx] = (unsigned short)(4 * (r * NT + t) + (p & 3));
        }
      }
    }
  }
}

__global__ void __launch_bounds__(NT, 6)
topk_scatter_kernel(const float* __restrict__ x, const int* __restrict__ kptr,
                    float* __restrict__ out) {
  const int t    = threadIdx.x;
  const int lane = t & 63;
  const int wid  = t >> 6;
  const long long row = blockIdx.x;
  const int K = *kptr;   // 128

  __shared__ int redA[NW], redB[NW];        // bracket counts per wave
  __shared__ int red2[2][NW];               // fallback reduce, parity-buffered
  __shared__ unsigned int   cand[CAP];      // window candidate keys
  __shared__ unsigned short candcol[CAP];   // window candidate columns
  __shared__ int hist[NBIN];                // window histogram (wave0-built)
  __shared__ int cand_n;
  __shared__ int c2n;                       // wave0 bin-compaction counter
  __shared__ unsigned int sT;               // broadcast: threshold key
  __shared__ int sE, sR;                    // broadcast: eq-count, keep-count
  __shared__ unsigned int flags[COLS / 32]; // fallback tie bitmask (2 KB);
                                            // reused as wave0's cand2[128]

  const uint4* xrow = reinterpret_cast<const uint4*>(x + row * COLS);
  v4f*         orow = reinterpret_cast<v4f*>(out + row * COLS);

  // Window [A, B): key range B-A = 0x59999A < 2^23, so bin = (k-A)>>17 < 64.
  const unsigned int A = f2key(1.9f);
  const unsigned int B = f2key(3.2f);

  if (t < NBIN) hist[t] = 0;
  if (t == 0) cand_n = 0;
  __syncthreads();                                   // barrier 0

  // ---- hot loop: pipelined load->transform->store + inline reg push ------
  int cwA = 0, cwB = 0;
  {
    uint4 bA[4], bB[4];
    load_chunk(xrow, t, 0, bA);
    load_chunk(xrow, t, 1, bB);
    proc_chunk(orow, cand, candcol, &cand_n, t, lane, 0, bA, A, B, cwA, cwB);
    load_chunk(xrow, t, 2, bA);
    proc_chunk(orow, cand, candcol, &cand_n, t, lane, 1, bB, A, B, cwA, cwB);
    load_chunk(xrow, t, 3, bB);
    proc_chunk(orow, cand, candcol, &cand_n, t, lane, 2, bA, A, B, cwA, cwB);
    proc_chunk(orow, cand, candcol, &cand_n, t, lane, 3, bB, A, B, cwA, cwB);
  }

  #pragma unroll
  for (int off = 32; off; off >>= 1) {
    cwA += __shfl_down(cwA, off);
    cwB += __shfl_down(cwB, off);
  }
  if (lane == 0) { redA[wid] = cwA; redB[wid] = cwB; }
  __syncthreads();                                   // barrier 1 (cheap now)

  int cA = 0, cBv = 0;
  #pragma unroll
  for (int w = 0; w < NW; ++w) { cA += redA[w]; cBv += redB[w]; }

  const bool fast = (cA >= K) && (cBv < K) && ((cA - cBv) <= CAP);

  if (fast) {
    const int NC = cA - cBv;                         // exact window count
    // ---- wave 0: build hist from cand list, then select (no barriers) ---
    if (wid == 0) {
      for (int j0 = 0; j0 < NC; j0 += 64) {
        const int j = j0 + lane;
        if (j < NC) atomicAdd(&hist[(cand[j] - A) >> 17], 1);
      }
      // suffix sums: suf[b] = count of window cands with bin >= b
      int suf = hist[lane];                          // NBIN == 64 lanes
      #pragma unroll
      for (int off = 1; off < 64; off <<= 1) {
        const int v = __shfl_down(suf, off);
        if (lane + off < 64) suf += v;
      }
      const unsigned long long m = __ballot(cBv + suf >= K);
      const int bstar = 63 - __clzll((long long)m);  // threshold bin
      const int s_b  = __shfl(suf, bstar);
      const int s_b1 = (bstar < 63) ? __shfl(suf, bstar + 1) : 0;
      const int nb = s_b - s_b1;                     // cands in bin (>=1)
      const unsigned int binlo = A + ((unsigned int)bstar << 17);
      const unsigned int binhi = binlo + (1u << 17) - 1u;
      unsigned int lo, hi;
      int cnt_lo, cnt_hi1;
      if (nb <= 128) {
        // compact bin-b* cands into cand2 (reuse flags); intra-wave ordered
        unsigned int* cand2 = (unsigned int*)flags;
        cand2[lane] = 0u; cand2[64 + lane] = 0u;     // 0 < binlo: never counts
        if (lane == 0) c2n = 0;
        for (int j0 = 0; j0 < NC; j0 += 64) {
          const int j = j0 + lane;
          const unsigned int v = (j < NC) ? cand[j] : 0u;
          if (v >= binlo && v <= binhi) {
            const int p = atomicAdd(&c2n, 1);
            cand2[p] = v;
          }
        }
        const unsigned int r0 = cand2[lane];
        const unsigned int r1 = cand2[64 + lane];
        lo = binlo; hi = binhi;
        cnt_lo = cBv + s_b; cnt_hi1 = cBv + s_b1;
        const int base2 = cBv + s_b1;
        while (lo < hi) {                            // exactly 17 iterations
          const unsigned int mid = lo + ((hi - lo) >> 1) + 1u;
          const int c = base2 + __popcll(__ballot(r0 >= mid))
                              + __popcll(__ballot(r1 >= mid));
          if (c >= K) { lo = mid; cnt_lo = c; }
          else        { hi = mid - 1u; cnt_hi1 = c; }
        }
      } else {
        // adversarial bin (>128 cands): scan full cand list per iteration
        lo = A; hi = B - 1u; cnt_lo = cA; cnt_hi1 = cBv;
        while (lo < hi) {
          const unsigned int mid = lo + ((hi - lo) >> 1) + 1u;
          int c = cBv;
          for (int j0 = 0; j0 < NC; j0 += 64) {
            const unsigned int v = (j0 + lane < NC) ? cand[j0 + lane] : 0u;
            c += __popcll(__ballot(v >= mid));
          }
          if (c >= K) { lo = mid; cnt_lo = c; }
          else        { hi = mid - 1u; cnt_hi1 = c; }
        }
      }
      if (lane == 0) { sT = lo; sE = cnt_lo - cnt_hi1; sR = K - cnt_hi1; }
    }
    __syncthreads();                                 // barrier 2 (cheap now)

    // ---- fix-up: scatter kept window values (~K - cB scalar stores) ------
    // Same-address overwrite of phase-1 stores: ordered by barrier 2's
    // vmcnt(0) drain (cheap at L2); scalars merge into L2-resident lines.
    const unsigned int T = sT;
    const int Ev = sE, Rv = sR;
    const bool needR = (Ev != Rv);     // duplicates straddling the boundary
    float* orow_s = out + row * COLS;
    for (int i = t; i < NC; i += NT) {
      const unsigned int k = cand[i];
      if (k < T) continue;
      const int col = candcol[i];
      if (needR && k == T) {
        int rk = 0;
        for (int j = 0; j < NC; ++j)
          rk += (cand[j] == T && candcol[j] < col) ? 1 : 0;
        if (rk >= Rv) continue;        // keep only R lowest-indexed ties
      }
      orow_s[col] = key2f(k);
    }
    return;
  }

  // ---- exact fallback: bitwise bisection with global re-reads ------------
  unsigned int T;
  int Ev, Rv;
  {
    unsigned int lo = 0u, hi = 0xFFFFFFFFu;
    int cnt_lo = COLS, cnt_hi1 = 0;
    int base = 0, cN = 0;
    bool compacted = false;
    int par = 0;
    while (lo < hi) {
      const unsigned int mid = lo + ((hi - lo) >> 1) + 1u;
      int c;
      if (!compacted) {
        int cw = 0;
        for (int r = 0; r < GPT; ++r) {
          const uint4 u = xrow[r * NT + t];
          cw += (f2key(__uint_as_float(u.x)) >= mid);
          cw += (f2key(__uint_as_float(u.y)) >= mid);
          cw += (f2key(__uint_as_float(u.z)) >= mid);
          cw += (f2key(__uint_as_float(u.w)) >= mid);
        }
        #pragma unroll
        for (int off = 32; off; off >>= 1) cw += __shfl_down(cw, off);
        if (lane == 0) red2[par][wid] = cw;
        __syncthreads();
        c = 0;
        #pragma unroll
        for (int w = 0; w < NW; ++w) c += red2[par][w];
        par ^= 1;
      } else {
        int cw = 0;
        for (int j0 = 0; j0 < cN; j0 += 64) {
          const int j = j0 + lane;
          const unsigned int v = (j < cN) ? cand[j] : 0u;
          cw += __popcll(__ballot(v >= mid));
        }
        c = base + cw;
      }
      if (c >= K) { lo = mid; cnt_lo = c; }
      else        { hi = mid - 1u; cnt_hi1 = c; }

      if (!compacted && lo < hi && (cnt_lo - cnt_hi1) <= CAP) {
        if (t == 0) cand_n = 0;
        __syncthreads();
        for (int r = 0; r < GPT; ++r) {
          const uint4 u = xrow[r * NT + t];
          const unsigned int kk[4] = {
            f2key(__uint_as_float(u.x)), f2key(__uint_as_float(u.y)),
            f2key(__uint_as_float(u.z)), f2key(__uint_as_float(u.w)) };
          #pragma unroll
          for (int j = 0; j < 4; ++j) {
            if (kk[j] >= lo && kk[j] <= hi) {
              const int p = atomicAdd(&cand_n, 1);
              if (p < CAP) cand[p] = kk[j];
            }
          }
        }
        __syncthreads();
        cN = cnt_lo - cnt_hi1;
        base = cnt_hi1;
        compacted = true;
      }
    }
    T = lo; Ev = cnt_lo - cnt_hi1; Rv = K - cnt_hi1;
  }

  const bool needR = (Ev != Rv);
  if (needR) {
    for (int w = t; w < COLS / 32; w += NT) flags[w] = 0u;
    __syncthreads();
    for (int r = 0; r < GPT; ++r) {
      const int g = r * NT + t;
      const uint4 u = xrow[g];
      const unsigned int kk[4] = {
        f2key(__uint_as_float(u.x)), f2key(__uint_as_float(u.y)),
        f2key(__uint_as_float(u.z)), f2key(__uint_as_float(u.w)) };
      #pragma unroll
      for (int j = 0; j < 4; ++j) {
        if (kk[j] == T) {
          const int col = 4 * g + j;
          atomicOr(&flags[col >> 5], 1u << (col & 31));
        }
      }
    }
    __syncthreads();
  }

  // full write pass (fallback only; overwrites phase-1 stores, same thread)
  for (int r = 0; r < GPT; ++r) {
    const int g = r * NT + t;
    const uint4 u = xrow[g];
    const unsigned int kk[4] = {
      f2key(__uint_as_float(u.x)), f2key(__uint_as_float(u.y)),
      f2key(__uint_as_float(u.z)), f2key(__uint_as_float(u.w)) };
    v4f vals;
    #pragma unroll
    for (int j = 0; j < 4; ++j) {
      bool keep;
      if (kk[j] > T) {
        keep = true;
      } else if (kk[j] == T) {
        if (!needR) {
          keep = true;
        } else {
          const int col = 4 * g + j;
          const int w_hi = col >> 5;
          int rank = 0;
          for (int w = 0; w < w_hi; ++w) rank += __popc(flags[w]);
          rank += __popc(flags[w_hi] & ((1u << (col & 31)) - 1u));
          keep = (rank < Rv);
        }
      } else {
        keep = false;
      }
      vals[j] = keep ? key2f(kk[j]) : 0.0f;
    }
    orow[g] = vals;
  }
}

extern "C" void kernel_launch(void* const* d_in, const int* in_sizes, int n_in,
                              void* d_out, int out_size, void* d_ws, size_t ws_size,
                              hipStream_t stream) {
  const float* x    = (const float*)d_in[0];
  const int*   kptr = (const int*)d_in[1];
  float*       out  = (float*)d_out;
  const int rows = in_sizes[0] / COLS;  // 4096
  topk_scatter_kernel<<<rows, NT, 0, stream>>>(x, kptr, out);
}